// Round 1
// baseline (874.211 us; speedup 1.0000x reference)
//
#include <hip/hip_runtime.h>

typedef __attribute__((ext_vector_type(8))) short bf16x8;
typedef __attribute__((ext_vector_type(4))) float f32x4;

static __device__ __forceinline__ unsigned short f2bf(float f) {
    unsigned int u = __builtin_bit_cast(unsigned int, f);
    u += 0x7fffu + ((u >> 16) & 1u);          // round-to-nearest-even
    return (unsigned short)(u >> 16);
}
static __device__ __forceinline__ float bf2f(unsigned short h) {
    unsigned int u = ((unsigned int)h) << 16;
    return __builtin_bit_cast(float, u);
}

// ---------------- prep kernels ----------------

__global__ void cvt_x_kernel(const float* __restrict__ x, unsigned short* __restrict__ xb, int total8) {
    int i = blockIdx.x * blockDim.x + threadIdx.x;
    if (i >= total8) return;
    const float4* p = reinterpret_cast<const float4*>(x) + (size_t)i * 2;
    float4 a = p[0], b = p[1];
    bf16x8 o;
    o[0] = (short)f2bf(a.x); o[1] = (short)f2bf(a.y); o[2] = (short)f2bf(a.z); o[3] = (short)f2bf(a.w);
    o[4] = (short)f2bf(b.x); o[5] = (short)f2bf(b.y); o[6] = (short)f2bf(b.z); o[7] = (short)f2bf(b.w);
    reinterpret_cast<bf16x8*>(xb)[i] = o;
}

__global__ void cvt_neigh_kernel(const int* __restrict__ nh, int* __restrict__ nt, int n) {
    int i = blockIdx.x * blockDim.x + threadIdx.x;
    if (i >= n) return;
    #pragma unroll
    for (int k = 0; k < 27; ++k)
        nt[(size_t)k * n + i] = nh[(size_t)i * 27 + k];
}

// W [k][cin][cout] f32  ->  WT [k][cout][cin] bf16
__global__ void cvt_w_kernel(const float* __restrict__ w, unsigned short* __restrict__ wt) {
    int i = blockIdx.x * blockDim.x + threadIdx.x;
    if (i >= 27 * 4096) return;
    int k = i >> 12;
    int cout = (i >> 6) & 63;
    int cin = i & 63;
    wt[i] = f2bf(w[((size_t)(k * 64 + cin)) * 64 + cout]);
}

// ---------------- gathered GEMM (octree conv) ----------------
// y[n, d] = sum_k sum_c xb[nt[k][n], c] * WT[k][d][c];   also per-channel partial sums/sumsq.
__global__ __launch_bounds__(256) void conv_mfma(
    const unsigned short* __restrict__ xb,   // [n][64] bf16
    const int* __restrict__ nt,              // [27][n]
    const unsigned short* __restrict__ wt,   // [27][64][64] bf16 (cout-major)
    unsigned short* __restrict__ y,          // [n][64] bf16 (raw conv out)
    float* __restrict__ pS,                  // [grid][64]
    float* __restrict__ pQ,                  // [grid][64]
    int n)
{
    const int wid  = threadIdx.x >> 6;
    const int lane = threadIdx.x & 63;
    const int lr   = lane & 15;
    const int lg   = lane >> 4;
    const int base = blockIdx.x * 256 + wid * 64;

    f32x4 acc[4][4];
    #pragma unroll
    for (int t = 0; t < 4; ++t)
        #pragma unroll
        for (int c = 0; c < 4; ++c)
            acc[t][c] = (f32x4){0.f, 0.f, 0.f, 0.f};

    for (int k = 0; k < 27; ++k) {
        const unsigned short* wk = wt + k * 4096;
        bf16x8 B[2][4];
        #pragma unroll
        for (int c = 0; c < 4; ++c)
            #pragma unroll
            for (int s = 0; s < 2; ++s)
                B[s][c] = *reinterpret_cast<const bf16x8*>(wk + (c * 16 + lr) * 64 + s * 32 + lg * 8);

        const int* ntk = nt + (size_t)k * (size_t)n;
        #pragma unroll
        for (int t = 0; t < 4; ++t) {
            int r = base + t * 16 + lr;
            r = r < n ? r : n - 1;
            const int idx = ntk[r];
            const unsigned short* xrow = xb + (size_t)idx * 64;
            bf16x8 A0 = *reinterpret_cast<const bf16x8*>(xrow + lg * 8);
            bf16x8 A1 = *reinterpret_cast<const bf16x8*>(xrow + 32 + lg * 8);
            #pragma unroll
            for (int c = 0; c < 4; ++c)
                acc[t][c] = __builtin_amdgcn_mfma_f32_16x16x32_bf16(A0, B[0][c], acc[t][c], 0, 0, 0);
            #pragma unroll
            for (int c = 0; c < 4; ++c)
                acc[t][c] = __builtin_amdgcn_mfma_f32_16x16x32_bf16(A1, B[1][c], acc[t][c], 0, 0, 0);
        }
    }

    // epilogue: store bf16 conv output + per-channel partial stats
    float s1[4] = {0.f, 0.f, 0.f, 0.f};
    float s2[4] = {0.f, 0.f, 0.f, 0.f};
    #pragma unroll
    for (int t = 0; t < 4; ++t) {
        #pragma unroll
        for (int rg = 0; rg < 4; ++rg) {
            int row = base + t * 16 + lg * 4 + rg;   // C/D layout: row=(lane>>4)*4+reg
            if (row < n) {
                #pragma unroll
                for (int c = 0; c < 4; ++c) {
                    float v = acc[t][c][rg];
                    s1[c] += v;
                    s2[c] += v * v;
                    y[(size_t)row * 64 + c * 16 + lr] = f2bf(v);   // col = c*16 + (lane&15)
                }
            }
        }
    }
    #pragma unroll
    for (int c = 0; c < 4; ++c) {
        s1[c] += __shfl_xor(s1[c], 16);
        s1[c] += __shfl_xor(s1[c], 32);
        s2[c] += __shfl_xor(s2[c], 16);
        s2[c] += __shfl_xor(s2[c], 32);
    }
    __shared__ float ls1[4][64];
    __shared__ float ls2[4][64];
    if (lane < 16) {
        #pragma unroll
        for (int c = 0; c < 4; ++c) {
            ls1[wid][c * 16 + lane] = s1[c];
            ls2[wid][c * 16 + lane] = s2[c];
        }
    }
    __syncthreads();
    if (threadIdx.x < 128) {
        int c = threadIdx.x & 63;
        float v;
        if (threadIdx.x < 64)
            v = ls1[0][c] + ls1[1][c] + ls1[2][c] + ls1[3][c];
        else
            v = ls2[0][c] + ls2[1][c] + ls2[2][c] + ls2[3][c];
        (threadIdx.x < 64 ? pS : pQ)[(size_t)blockIdx.x * 64 + c] = v;
    }
}

// ---------------- BN finalize: scale/shift from partials ----------------
__global__ void bn_stats_kernel(const float* __restrict__ pS, const float* __restrict__ pQ,
                                const float* __restrict__ gamma, const float* __restrict__ beta,
                                float* __restrict__ bnp, int nb, float invN) {
    int c = threadIdx.x;
    if (c >= 64) return;
    float S = 0.f, Q = 0.f;
    for (int b = 0; b < nb; ++b) {
        S += pS[(size_t)b * 64 + c];
        Q += pQ[(size_t)b * 64 + c];
    }
    float mean = S * invN;
    float var  = Q * invN - mean * mean;
    float sc   = gamma[c] * rsqrtf(var + 1e-5f);
    bnp[c]      = sc;
    bnp[64 + c] = beta[c] - mean * sc;
}

// ---------------- BN+ReLU -> bf16 (input of conv2) ----------------
__global__ void bn_relu_kernel(const unsigned short* __restrict__ y, const float* __restrict__ bnp,
                               unsigned short* __restrict__ yn, int total8) {
    int i = blockIdx.x * blockDim.x + threadIdx.x;
    if (i >= total8) return;
    bf16x8 v = reinterpret_cast<const bf16x8*>(y)[i];
    int c0 = (i * 8) & 63;
    bf16x8 o;
    #pragma unroll
    for (int j = 0; j < 8; ++j) {
        float f = bf2f((unsigned short)v[j]) * bnp[c0 + j] + bnp[64 + c0 + j];
        f = fmaxf(f, 0.f);
        o[j] = (short)f2bf(f);
    }
    reinterpret_cast<bf16x8*>(yn)[i] = o;
}

// ---------------- final: BN2 + residual + ReLU -> f32 out, plus depth ----------------
__global__ void final_kernel(const unsigned short* __restrict__ y2, const float* __restrict__ x,
                             const float* __restrict__ bnp, const int* __restrict__ depth,
                             float* __restrict__ out, int total8, int n) {
    int i = blockIdx.x * blockDim.x + threadIdx.x;
    if (i == 0) out[(size_t)n * 64] = (float)depth[0];
    if (i >= total8) return;
    bf16x8 v = reinterpret_cast<const bf16x8*>(y2)[i];
    const float4* xp = reinterpret_cast<const float4*>(x) + (size_t)i * 2;
    float4 xa = xp[0], xbv = xp[1];
    int c0 = (i * 8) & 63;
    float r[8];
    #pragma unroll
    for (int j = 0; j < 8; ++j)
        r[j] = bf2f((unsigned short)v[j]) * bnp[c0 + j] + bnp[64 + c0 + j];
    r[0] += xa.x;  r[1] += xa.y;  r[2] += xa.z;  r[3] += xa.w;
    r[4] += xbv.x; r[5] += xbv.y; r[6] += xbv.z; r[7] += xbv.w;
    float4* op = reinterpret_cast<float4*>(out) + (size_t)i * 2;
    float4 o0 = {fmaxf(r[0], 0.f), fmaxf(r[1], 0.f), fmaxf(r[2], 0.f), fmaxf(r[3], 0.f)};
    float4 o1 = {fmaxf(r[4], 0.f), fmaxf(r[5], 0.f), fmaxf(r[6], 0.f), fmaxf(r[7], 0.f)};
    op[0] = o0;
    op[1] = o1;
}

extern "C" void kernel_launch(void* const* d_in, const int* in_sizes, int n_in,
                              void* d_out, int out_size, void* d_ws, size_t ws_size,
                              hipStream_t stream) {
    const float* x     = (const float*)d_in[0];
    const int*   neigh = (const int*)d_in[1];
    const int*   depth = (const int*)d_in[2];
    const float* W1    = (const float*)d_in[3];
    const float* g1    = (const float*)d_in[4];
    const float* b1    = (const float*)d_in[5];
    const float* W2    = (const float*)d_in[6];
    const float* g2    = (const float*)d_in[7];
    const float* b2    = (const float*)d_in[8];
    float* out = (float*)d_out;

    const int n      = in_sizes[0] / 64;   // 200000
    const int total8 = in_sizes[0] / 8;    // N*C/8
    const int nb     = (n + 255) / 256;    // conv grid (782)

    char* ws = (char*)d_ws;
    size_t off = 0;
    auto carve = [&](size_t bytes) -> char* {
        char* p = ws + off;
        off += (bytes + 255) & ~((size_t)255);
        return p;
    };
    unsigned short* bufA = (unsigned short*)carve((size_t)n * 64 * 2); // xb, later y1n
    unsigned short* bufB = (unsigned short*)carve((size_t)n * 64 * 2); // y1, later y2
    int*            nt   = (int*)carve((size_t)27 * n * 4);
    unsigned short* w1t  = (unsigned short*)carve(27 * 4096 * 2);
    unsigned short* w2t  = (unsigned short*)carve(27 * 4096 * 2);
    float*          pS   = (float*)carve((size_t)nb * 64 * 4);
    float*          pQ   = (float*)carve((size_t)nb * 64 * 4);
    float*          bnp1 = (float*)carve(128 * 4);
    float*          bnp2 = (float*)carve(128 * 4);

    const int gcvt = (total8 + 255) / 256;
    const int gw   = (27 * 4096 + 255) / 256;
    const float invN = 1.0f / (float)n;

    cvt_x_kernel<<<gcvt, 256, 0, stream>>>(x, bufA, total8);
    cvt_neigh_kernel<<<nb, 256, 0, stream>>>(neigh, nt, n);
    cvt_w_kernel<<<gw, 256, 0, stream>>>(W1, w1t);
    cvt_w_kernel<<<gw, 256, 0, stream>>>(W2, w2t);

    conv_mfma<<<nb, 256, 0, stream>>>(bufA, nt, w1t, bufB, pS, pQ, n);
    bn_stats_kernel<<<1, 64, 0, stream>>>(pS, pQ, g1, b1, bnp1, nb, invN);
    bn_relu_kernel<<<gcvt, 256, 0, stream>>>(bufB, bnp1, bufA, total8);

    conv_mfma<<<nb, 256, 0, stream>>>(bufA, nt, w2t, bufB, pS, pQ, n);
    bn_stats_kernel<<<1, 64, 0, stream>>>(pS, pQ, g2, b2, bnp2, nb, invN);
    final_kernel<<<gcvt, 256, 0, stream>>>(bufB, x, bnp2, depth, out, total8, n);
}

// Round 2
// 355.087 us; speedup vs baseline: 2.4620x; 2.4620x over previous
//
#include <hip/hip_runtime.h>

typedef __attribute__((ext_vector_type(8))) short bf16x8;
typedef __attribute__((ext_vector_type(4))) float f32x4;

static __device__ __forceinline__ unsigned short f2bf(float f) {
    unsigned int u = __builtin_bit_cast(unsigned int, f);
    u += 0x7fffu + ((u >> 16) & 1u);          // round-to-nearest-even
    return (unsigned short)(u >> 16);
}
static __device__ __forceinline__ float bf2f(unsigned short h) {
    unsigned int u = ((unsigned int)h) << 16;
    return __builtin_bit_cast(float, u);
}

// ---------------- prep kernels ----------------

__global__ void cvt_x_kernel(const float* __restrict__ x, unsigned short* __restrict__ xb, int total8) {
    int i = blockIdx.x * blockDim.x + threadIdx.x;
    if (i >= total8) return;
    const float4* p = reinterpret_cast<const float4*>(x) + (size_t)i * 2;
    float4 a = p[0], b = p[1];
    bf16x8 o;
    o[0] = (short)f2bf(a.x); o[1] = (short)f2bf(a.y); o[2] = (short)f2bf(a.z); o[3] = (short)f2bf(a.w);
    o[4] = (short)f2bf(b.x); o[5] = (short)f2bf(b.y); o[6] = (short)f2bf(b.z); o[7] = (short)f2bf(b.w);
    reinterpret_cast<bf16x8*>(xb)[i] = o;
}

// W [k][cin][cout] f32  ->  WT [k][cout][cin] bf16
__global__ void cvt_w_kernel(const float* __restrict__ w, unsigned short* __restrict__ wt) {
    int i = blockIdx.x * blockDim.x + threadIdx.x;
    if (i >= 27 * 4096) return;
    int k = i >> 12;
    int cout = (i >> 6) & 63;
    int cin = i & 63;
    wt[i] = f2bf(w[((size_t)(k * 64 + cin)) * 64 + cout]);
}

// ---------------- gathered GEMM (octree conv) ----------------
// Block = 64 rows x 64 cols. 4 waves; wave w owns col-quarter w*16..w*16+15.
// Per k: gather-stage 64 rows x 64ch bf16 (8KB) into LDS via global_load_lds
// (XOR-swizzled source so ds_read_b128 frag reads are conflict-free), then MFMA.
__global__ __launch_bounds__(256) void conv_mfma(
    const unsigned short* __restrict__ xb,   // [n][64] bf16
    const int* __restrict__ nh,              // [n][27] neighbor indices
    const unsigned short* __restrict__ wt,   // [27][64][64] bf16 (cout-major)
    unsigned short* __restrict__ y,          // [n][64] bf16 (raw conv out)
    float* __restrict__ pS,                  // [64][grid] transposed partials
    float* __restrict__ pQ,                  // [64][grid]
    int n)
{
    __shared__ unsigned short Atile[4096];   // 64 rows x 64 shorts (8 KB)

    const int tid  = threadIdx.x;
    const int wid  = tid >> 6;
    const int lane = tid & 63;
    const int lr   = lane & 15;
    const int lg   = lane >> 4;
    const int base = blockIdx.x * 64;

    // staging geometry: instr j covers rows j*32 + (tid>>3), 16B slot (tid&7)
    const int srow  = tid >> 3;              // 0..31
    const int sslot = tid & 7;
    const int xoff  = (sslot ^ (srow & 7)) * 8;   // swizzled source slot (shorts)
    int gr0 = base + srow;        if (gr0 >= n) gr0 = n - 1;
    int gr1 = base + 32 + srow;   if (gr1 >= n) gr1 = n - 1;
    const long no0 = (long)gr0 * 27;
    const long no1 = (long)gr1 * 27;
    unsigned short* dst0 = &Atile[wid * 512];          // wave-uniform LDS base (bytes wid*1024)
    unsigned short* dst1 = &Atile[2048 + wid * 512];

    f32x4 acc[4];
    #pragma unroll
    for (int t = 0; t < 4; ++t) acc[t] = (f32x4){0.f, 0.f, 0.f, 0.f};

    const unsigned short* wB = wt + (wid * 16 + lr) * 64 + lg * 8;

    for (int k = 0; k < 27; ++k) {
        const int i0 = nh[no0 + k];
        const int i1 = nh[no1 + k];
        __builtin_amdgcn_global_load_lds(
            (const __attribute__((address_space(1))) unsigned int*)(xb + (size_t)i0 * 64 + xoff),
            (__attribute__((address_space(3))) unsigned int*)dst0, 16, 0, 0);
        __builtin_amdgcn_global_load_lds(
            (const __attribute__((address_space(1))) unsigned int*)(xb + (size_t)i1 * 64 + xoff),
            (__attribute__((address_space(3))) unsigned int*)dst1, 16, 0, 0);
        __syncthreads();    // compiler drains vmcnt before s_barrier -> stage complete

        bf16x8 B0 = *reinterpret_cast<const bf16x8*>(wB + k * 4096);
        bf16x8 B1 = *reinterpret_cast<const bf16x8*>(wB + k * 4096 + 32);
        #pragma unroll
        for (int t = 0; t < 4; ++t) {
            const int row = t * 16 + lr;
            const int sw  = (row & 7) * 8;
            bf16x8 A0 = *reinterpret_cast<const bf16x8*>(&Atile[row * 64 + ((lg * 8) ^ sw)]);
            bf16x8 A1 = *reinterpret_cast<const bf16x8*>(&Atile[row * 64 + (((4 + lg) * 8) ^ sw)]);
            acc[t] = __builtin_amdgcn_mfma_f32_16x16x32_bf16(A0, B0, acc[t], 0, 0, 0);
            acc[t] = __builtin_amdgcn_mfma_f32_16x16x32_bf16(A1, B1, acc[t], 0, 0, 0);
        }
        __syncthreads();    // all ds_reads done before next k overwrites Atile
    }

    // epilogue: store bf16 conv output + per-channel partial stats
    float s1 = 0.f, s2 = 0.f;
    #pragma unroll
    for (int t = 0; t < 4; ++t) {
        #pragma unroll
        for (int rg = 0; rg < 4; ++rg) {
            const int row = base + t * 16 + lg * 4 + rg;   // C/D: row=(lane>>4)*4+reg
            const float v = acc[t][rg];
            if (row < n) {
                s1 += v;
                s2 += v * v;
                y[(size_t)row * 64 + wid * 16 + lr] = f2bf(v);   // col = wid*16 + (lane&15)
            }
        }
    }
    s1 += __shfl_xor(s1, 16); s1 += __shfl_xor(s1, 32);
    s2 += __shfl_xor(s2, 16); s2 += __shfl_xor(s2, 32);
    if (lane < 16) {
        const int ch = wid * 16 + lane;
        pS[(size_t)ch * gridDim.x + blockIdx.x] = s1;
        pQ[(size_t)ch * gridDim.x + blockIdx.x] = s2;
    }
}

// ---------------- BN finalize: parallel reduce of partials ----------------
__global__ __launch_bounds__(256) void bn_stats_kernel(
        const float* __restrict__ pS, const float* __restrict__ pQ,
        const float* __restrict__ gamma, const float* __restrict__ beta,
        float* __restrict__ bnp, int nb, float invN) {
    const int c = blockIdx.x;          // channel
    const int tid = threadIdx.x;
    float S = 0.f, Q = 0.f;
    for (int b = tid; b < nb; b += 256) {
        S += pS[(size_t)c * nb + b];
        Q += pQ[(size_t)c * nb + b];
    }
    #pragma unroll
    for (int o = 1; o < 64; o <<= 1) {
        S += __shfl_xor(S, o);
        Q += __shfl_xor(Q, o);
    }
    __shared__ float sh[8];
    if ((tid & 63) == 0) { sh[(tid >> 6) * 2] = S; sh[(tid >> 6) * 2 + 1] = Q; }
    __syncthreads();
    if (tid == 0) {
        S = sh[0] + sh[2] + sh[4] + sh[6];
        Q = sh[1] + sh[3] + sh[5] + sh[7];
        const float mean = S * invN;
        const float var  = Q * invN - mean * mean;
        const float sc   = gamma[c] * rsqrtf(var + 1e-5f);
        bnp[c]      = sc;
        bnp[64 + c] = beta[c] - mean * sc;
    }
}

// ---------------- BN+ReLU -> bf16 (input of conv2) ----------------
__global__ void bn_relu_kernel(const unsigned short* __restrict__ y, const float* __restrict__ bnp,
                               unsigned short* __restrict__ yn, int total8) {
    int i = blockIdx.x * blockDim.x + threadIdx.x;
    if (i >= total8) return;
    bf16x8 v = reinterpret_cast<const bf16x8*>(y)[i];
    int c0 = (i * 8) & 63;
    bf16x8 o;
    #pragma unroll
    for (int j = 0; j < 8; ++j) {
        float f = bf2f((unsigned short)v[j]) * bnp[c0 + j] + bnp[64 + c0 + j];
        f = fmaxf(f, 0.f);
        o[j] = (short)f2bf(f);
    }
    reinterpret_cast<bf16x8*>(yn)[i] = o;
}

// ---------------- final: BN2 + residual + ReLU -> f32 out, plus depth ----------------
__global__ void final_kernel(const unsigned short* __restrict__ y2, const float* __restrict__ x,
                             const float* __restrict__ bnp, const int* __restrict__ depth,
                             float* __restrict__ out, int total8, int n) {
    int i = blockIdx.x * blockDim.x + threadIdx.x;
    if (i == 0) out[(size_t)n * 64] = (float)depth[0];
    if (i >= total8) return;
    bf16x8 v = reinterpret_cast<const bf16x8*>(y2)[i];
    const float4* xp = reinterpret_cast<const float4*>(x) + (size_t)i * 2;
    float4 xa = xp[0], xbv = xp[1];
    int c0 = (i * 8) & 63;
    float r[8];
    #pragma unroll
    for (int j = 0; j < 8; ++j)
        r[j] = bf2f((unsigned short)v[j]) * bnp[c0 + j] + bnp[64 + c0 + j];
    r[0] += xa.x;  r[1] += xa.y;  r[2] += xa.z;  r[3] += xa.w;
    r[4] += xbv.x; r[5] += xbv.y; r[6] += xbv.z; r[7] += xbv.w;
    float4* op = reinterpret_cast<float4*>(out) + (size_t)i * 2;
    float4 o0 = {fmaxf(r[0], 0.f), fmaxf(r[1], 0.f), fmaxf(r[2], 0.f), fmaxf(r[3], 0.f)};
    float4 o1 = {fmaxf(r[4], 0.f), fmaxf(r[5], 0.f), fmaxf(r[6], 0.f), fmaxf(r[7], 0.f)};
    op[0] = o0;
    op[1] = o1;
}

extern "C" void kernel_launch(void* const* d_in, const int* in_sizes, int n_in,
                              void* d_out, int out_size, void* d_ws, size_t ws_size,
                              hipStream_t stream) {
    const float* x     = (const float*)d_in[0];
    const int*   neigh = (const int*)d_in[1];
    const int*   depth = (const int*)d_in[2];
    const float* W1    = (const float*)d_in[3];
    const float* g1    = (const float*)d_in[4];
    const float* b1    = (const float*)d_in[5];
    const float* W2    = (const float*)d_in[6];
    const float* g2    = (const float*)d_in[7];
    const float* b2    = (const float*)d_in[8];
    float* out = (float*)d_out;

    const int n      = in_sizes[0] / 64;   // 200000
    const int total8 = in_sizes[0] / 8;    // N*C/8
    const int nb     = (n + 63) / 64;      // conv grid (3125)

    char* ws = (char*)d_ws;
    size_t off = 0;
    auto carve = [&](size_t bytes) -> char* {
        char* p = ws + off;
        off += (bytes + 255) & ~((size_t)255);
        return p;
    };
    unsigned short* bufA = (unsigned short*)carve((size_t)n * 64 * 2); // xb, later y1n
    unsigned short* bufB = (unsigned short*)carve((size_t)n * 64 * 2); // y1, later y2
    unsigned short* w1t  = (unsigned short*)carve(27 * 4096 * 2);
    unsigned short* w2t  = (unsigned short*)carve(27 * 4096 * 2);
    float*          pS   = (float*)carve((size_t)nb * 64 * 4);
    float*          pQ   = (float*)carve((size_t)nb * 64 * 4);
    float*          bnp1 = (float*)carve(128 * 4);
    float*          bnp2 = (float*)carve(128 * 4);

    const int gcvt = (total8 + 255) / 256;
    const int gw   = (27 * 4096 + 255) / 256;
    const float invN = 1.0f / (float)n;

    cvt_x_kernel<<<gcvt, 256, 0, stream>>>(x, bufA, total8);
    cvt_w_kernel<<<gw, 256, 0, stream>>>(W1, w1t);
    cvt_w_kernel<<<gw, 256, 0, stream>>>(W2, w2t);

    conv_mfma<<<nb, 256, 0, stream>>>(bufA, neigh, w1t, bufB, pS, pQ, n);
    bn_stats_kernel<<<64, 256, 0, stream>>>(pS, pQ, g1, b1, bnp1, nb, invN);
    bn_relu_kernel<<<gcvt, 256, 0, stream>>>(bufB, bnp1, bufA, total8);

    conv_mfma<<<nb, 256, 0, stream>>>(bufA, neigh, w2t, bufB, pS, pQ, n);
    bn_stats_kernel<<<64, 256, 0, stream>>>(pS, pQ, g2, b2, bnp2, nb, invN);
    final_kernel<<<gcvt, 256, 0, stream>>>(bufB, x, bnp2, depth, out, total8, n);
}

// Round 3
// 281.995 us; speedup vs baseline: 3.1001x; 1.2592x over previous
//
#include <hip/hip_runtime.h>

typedef __attribute__((ext_vector_type(8))) short bf16x8;
typedef __attribute__((ext_vector_type(4))) float f32x4;

static __device__ __forceinline__ unsigned short f2bf(float f) {
    unsigned int u = __builtin_bit_cast(unsigned int, f);
    u += 0x7fffu + ((u >> 16) & 1u);          // round-to-nearest-even
    return (unsigned short)(u >> 16);
}
static __device__ __forceinline__ float bf2f(unsigned short h) {
    unsigned int u = ((unsigned int)h) << 16;
    return __builtin_bit_cast(float, u);
}

// ---------------- prep kernels ----------------

__global__ void cvt_x_kernel(const float* __restrict__ x, unsigned short* __restrict__ xb, int total8) {
    int i = blockIdx.x * blockDim.x + threadIdx.x;
    if (i >= total8) return;
    const float4* p = reinterpret_cast<const float4*>(x) + (size_t)i * 2;
    float4 a = p[0], b = p[1];
    bf16x8 o;
    o[0] = (short)f2bf(a.x); o[1] = (short)f2bf(a.y); o[2] = (short)f2bf(a.z); o[3] = (short)f2bf(a.w);
    o[4] = (short)f2bf(b.x); o[5] = (short)f2bf(b.y); o[6] = (short)f2bf(b.z); o[7] = (short)f2bf(b.w);
    reinterpret_cast<bf16x8*>(xb)[i] = o;
}

// W [k][cin][cout] f32 -> WT [k][cout][cin] bf16, both weight tensors in one launch
__global__ void cvt_w_kernel(const float* __restrict__ w1, const float* __restrict__ w2,
                             unsigned short* __restrict__ wt1, unsigned short* __restrict__ wt2) {
    int i = blockIdx.x * blockDim.x + threadIdx.x;
    if (i >= 2 * 27 * 4096) return;
    const float* w = (i < 27 * 4096) ? w1 : w2;
    unsigned short* wt = (i < 27 * 4096) ? wt1 : wt2;
    int j = (i < 27 * 4096) ? i : i - 27 * 4096;
    int k = j >> 12;
    int cout = (j >> 6) & 63;
    int cin = j & 63;
    wt[j] = f2bf(w[((size_t)(k * 64 + cin)) * 64 + cout]);
}

// ---------------- gathered GEMM (octree conv), double-buffered pipeline ----------------
// Block = 64 rows x 64 cols. 4 waves; wave w owns col-quarter w*16..w*16+15.
// Per tap: gather-stage 64x64ch bf16 (8KB) into LDS via global_load_lds (XOR-swizzled
// source). Prefetch depth 1 with counted vmcnt(4) (4 VMEM issues/phase: 2 B-frag loads
// + 2 global_load_lds); vmcnt never drains to 0 inside the loop.
__global__ __launch_bounds__(256, 6) void conv_mfma(
    const unsigned short* __restrict__ xb,   // [n][64] bf16
    const int* __restrict__ nh,              // [n][27] neighbor indices
    const unsigned short* __restrict__ wt,   // [27][64][64] bf16 (cout-major)
    unsigned short* __restrict__ y,          // [n][64] bf16 (raw conv out)
    float* __restrict__ pS,                  // [64][grid] transposed partials
    float* __restrict__ pQ,                  // [64][grid]
    int n)
{
    __shared__ unsigned short Atile[2][4096];   // 2 x (64 rows x 64 shorts) = 16 KB
    __shared__ int lidx[27 * 64];               // this block's neighbor indices (6.9 KB)

    const int tid  = threadIdx.x;
    const int wid  = tid >> 6;
    const int lane = tid & 63;
    const int lr   = lane & 15;
    const int lg   = lane >> 4;
    const int base = blockIdx.x * 64;

    // stage neighbor indices (row-major [row][k]); after this, idx reads are LDS-only
    for (int j = tid; j < 27 * 64; j += 256) {
        int row = j / 27;
        int kk  = j - row * 27;
        int gr  = base + row; if (gr >= n) gr = n - 1;
        lidx[j] = nh[(size_t)gr * 27 + kk];
    }
    __syncthreads();   // full drain: vmcnt queue empty entering the pipeline

    // staging geometry: instr covers rows (tid>>3) [+32], 16B slot (tid&7), XOR-swizzled src
    const int srow = tid >> 3;
    const int xoff = ((tid & 7) ^ (srow & 7)) * 8;
    const int so0  = srow * 27;
    const int so1  = (srow + 32) * 27;

    f32x4 acc[4];
    #pragma unroll
    for (int t = 0; t < 4; ++t) acc[t] = (f32x4){0.f, 0.f, 0.f, 0.f};

    const unsigned short* wB = wt + (wid * 16 + lr) * 64 + lg * 8;

#define ISSUE_TILE(kk, b) do {                                                        \
        const int i0_ = lidx[so0 + (kk)];                                             \
        const int i1_ = lidx[so1 + (kk)];                                             \
        __builtin_amdgcn_global_load_lds(                                             \
            (const __attribute__((address_space(1))) unsigned int*)(xb + (size_t)i0_ * 64 + xoff), \
            (__attribute__((address_space(3))) unsigned int*)(&Atile[b][wid * 512]), 16, 0, 0);    \
        __builtin_amdgcn_global_load_lds(                                             \
            (const __attribute__((address_space(1))) unsigned int*)(xb + (size_t)i1_ * 64 + xoff), \
            (__attribute__((address_space(3))) unsigned int*)(&Atile[b][2048 + wid * 512]), 16, 0, 0); \
    } while (0)

    auto compute = [&](const unsigned short* At, bf16x8 B0, bf16x8 B1) {
        #pragma unroll
        for (int t = 0; t < 4; ++t) {
            const int row = t * 16 + lr;
            const int sw  = (row & 7) * 8;
            bf16x8 A0 = *reinterpret_cast<const bf16x8*>(&At[row * 64 + ((lg * 8) ^ sw)]);
            bf16x8 A1 = *reinterpret_cast<const bf16x8*>(&At[row * 64 + (((4 + lg) * 8) ^ sw)]);
            acc[t] = __builtin_amdgcn_mfma_f32_16x16x32_bf16(A0, B0, acc[t], 0, 0, 0);
            acc[t] = __builtin_amdgcn_mfma_f32_16x16x32_bf16(A1, B1, acc[t], 0, 0, 0);
        }
    };

    // prologue: queue = [Ba(2), lds0(2)]
    bf16x8 Ba0 = *reinterpret_cast<const bf16x8*>(wB);
    bf16x8 Ba1 = *reinterpret_cast<const bf16x8*>(wB + 32);
    ISSUE_TILE(0, 0);

    for (int k = 0; k < 26; k += 2) {
        // phase A: prefetch tap k+1, compute tap k from buf0
        bf16x8 Bb0 = *reinterpret_cast<const bf16x8*>(wB + (k + 1) * 4096);
        bf16x8 Bb1 = *reinterpret_cast<const bf16x8*>(wB + (k + 1) * 4096 + 32);
        ISSUE_TILE(k + 1, 1);
        asm volatile("s_waitcnt vmcnt(4)" ::: "memory");   // retires Ba + lds(k); k+1 stays in flight
        __builtin_amdgcn_s_barrier();
        __builtin_amdgcn_sched_barrier(0);
        compute(&Atile[0][0], Ba0, Ba1);
        asm volatile("s_waitcnt lgkmcnt(0)" ::: "memory"); // all ds_reads of buf0 done
        __builtin_amdgcn_sched_barrier(0);
        __builtin_amdgcn_s_barrier();                      // buf0 safe to overwrite

        // phase B: prefetch tap k+2, compute tap k+1 from buf1
        Ba0 = *reinterpret_cast<const bf16x8*>(wB + (k + 2) * 4096);
        Ba1 = *reinterpret_cast<const bf16x8*>(wB + (k + 2) * 4096 + 32);
        ISSUE_TILE(k + 2, 0);
        asm volatile("s_waitcnt vmcnt(4)" ::: "memory");   // retires Bb + lds(k+1)
        __builtin_amdgcn_s_barrier();
        __builtin_amdgcn_sched_barrier(0);
        compute(&Atile[1][0], Bb0, Bb1);
        asm volatile("s_waitcnt lgkmcnt(0)" ::: "memory");
        __builtin_amdgcn_sched_barrier(0);
        __builtin_amdgcn_s_barrier();                      // buf1 safe to overwrite
    }
    // epilogue: tap 26 (queue = [Ba(2), lds26(2)])
    asm volatile("s_waitcnt vmcnt(0)" ::: "memory");
    __builtin_amdgcn_s_barrier();
    __builtin_amdgcn_sched_barrier(0);
    compute(&Atile[0][0], Ba0, Ba1);
#undef ISSUE_TILE

    // epilogue: store bf16 conv output + per-channel partial stats
    float s1 = 0.f, s2 = 0.f;
    #pragma unroll
    for (int t = 0; t < 4; ++t) {
        #pragma unroll
        for (int rg = 0; rg < 4; ++rg) {
            const int row = base + t * 16 + lg * 4 + rg;   // C/D: row=(lane>>4)*4+reg
            const float v = acc[t][rg];
            if (row < n) {
                s1 += v;
                s2 += v * v;
                y[(size_t)row * 64 + wid * 16 + lr] = f2bf(v);   // col = wid*16 + (lane&15)
            }
        }
    }
    s1 += __shfl_xor(s1, 16); s1 += __shfl_xor(s1, 32);
    s2 += __shfl_xor(s2, 16); s2 += __shfl_xor(s2, 32);
    if (lane < 16) {
        const int ch = wid * 16 + lane;
        pS[(size_t)ch * gridDim.x + blockIdx.x] = s1;
        pQ[(size_t)ch * gridDim.x + blockIdx.x] = s2;
    }
}

// ---------------- BN finalize: parallel reduce of partials ----------------
__global__ __launch_bounds__(256) void bn_stats_kernel(
        const float* __restrict__ pS, const float* __restrict__ pQ,
        const float* __restrict__ gamma, const float* __restrict__ beta,
        float* __restrict__ bnp, int nb, float invN) {
    const int c = blockIdx.x;          // channel
    const int tid = threadIdx.x;
    float S = 0.f, Q = 0.f;
    for (int b = tid; b < nb; b += 256) {
        S += pS[(size_t)c * nb + b];
        Q += pQ[(size_t)c * nb + b];
    }
    #pragma unroll
    for (int o = 1; o < 64; o <<= 1) {
        S += __shfl_xor(S, o);
        Q += __shfl_xor(Q, o);
    }
    __shared__ float sh[8];
    if ((tid & 63) == 0) { sh[(tid >> 6) * 2] = S; sh[(tid >> 6) * 2 + 1] = Q; }
    __syncthreads();
    if (tid == 0) {
        S = sh[0] + sh[2] + sh[4] + sh[6];
        Q = sh[1] + sh[3] + sh[5] + sh[7];
        const float mean = S * invN;
        const float var  = Q * invN - mean * mean;
        const float sc   = gamma[c] * rsqrtf(var + 1e-5f);
        bnp[c]      = sc;
        bnp[64 + c] = beta[c] - mean * sc;
    }
}

// ---------------- BN+ReLU -> bf16 (input of conv2) ----------------
__global__ void bn_relu_kernel(const unsigned short* __restrict__ y, const float* __restrict__ bnp,
                               unsigned short* __restrict__ yn, int total8) {
    int i = blockIdx.x * blockDim.x + threadIdx.x;
    if (i >= total8) return;
    bf16x8 v = reinterpret_cast<const bf16x8*>(y)[i];
    int c0 = (i * 8) & 63;
    bf16x8 o;
    #pragma unroll
    for (int j = 0; j < 8; ++j) {
        float f = bf2f((unsigned short)v[j]) * bnp[c0 + j] + bnp[64 + c0 + j];
        f = fmaxf(f, 0.f);
        o[j] = (short)f2bf(f);
    }
    reinterpret_cast<bf16x8*>(yn)[i] = o;
}

// ---------------- final: BN2 + residual + ReLU -> f32 out, plus depth ----------------
__global__ void final_kernel(const unsigned short* __restrict__ y2, const float* __restrict__ x,
                             const float* __restrict__ bnp, const int* __restrict__ depth,
                             float* __restrict__ out, int total8, int n) {
    int i = blockIdx.x * blockDim.x + threadIdx.x;
    if (i == 0) out[(size_t)n * 64] = (float)depth[0];
    if (i >= total8) return;
    bf16x8 v = reinterpret_cast<const bf16x8*>(y2)[i];
    const float4* xp = reinterpret_cast<const float4*>(x) + (size_t)i * 2;
    float4 xa = xp[0], xbv = xp[1];
    int c0 = (i * 8) & 63;
    float r[8];
    #pragma unroll
    for (int j = 0; j < 8; ++j)
        r[j] = bf2f((unsigned short)v[j]) * bnp[c0 + j] + bnp[64 + c0 + j];
    r[0] += xa.x;  r[1] += xa.y;  r[2] += xa.z;  r[3] += xa.w;
    r[4] += xbv.x; r[5] += xbv.y; r[6] += xbv.z; r[7] += xbv.w;
    float4* op = reinterpret_cast<float4*>(out) + (size_t)i * 2;
    float4 o0 = {fmaxf(r[0], 0.f), fmaxf(r[1], 0.f), fmaxf(r[2], 0.f), fmaxf(r[3], 0.f)};
    float4 o1 = {fmaxf(r[4], 0.f), fmaxf(r[5], 0.f), fmaxf(r[6], 0.f), fmaxf(r[7], 0.f)};
    op[0] = o0;
    op[1] = o1;
}

extern "C" void kernel_launch(void* const* d_in, const int* in_sizes, int n_in,
                              void* d_out, int out_size, void* d_ws, size_t ws_size,
                              hipStream_t stream) {
    const float* x     = (const float*)d_in[0];
    const int*   neigh = (const int*)d_in[1];
    const int*   depth = (const int*)d_in[2];
    const float* W1    = (const float*)d_in[3];
    const float* g1    = (const float*)d_in[4];
    const float* b1    = (const float*)d_in[5];
    const float* W2    = (const float*)d_in[6];
    const float* g2    = (const float*)d_in[7];
    const float* b2    = (const float*)d_in[8];
    float* out = (float*)d_out;

    const int n      = in_sizes[0] / 64;   // 200000
    const int total8 = in_sizes[0] / 8;    // N*C/8
    const int nb     = (n + 63) / 64;      // conv grid (3125)

    char* ws = (char*)d_ws;
    size_t off = 0;
    auto carve = [&](size_t bytes) -> char* {
        char* p = ws + off;
        off += (bytes + 255) & ~((size_t)255);
        return p;
    };
    unsigned short* bufA = (unsigned short*)carve((size_t)n * 64 * 2); // xb, later y1n
    unsigned short* bufB = (unsigned short*)carve((size_t)n * 64 * 2); // y1, later y2
    unsigned short* w1t  = (unsigned short*)carve(27 * 4096 * 2);
    unsigned short* w2t  = (unsigned short*)carve(27 * 4096 * 2);
    float*          pS   = (float*)carve((size_t)nb * 64 * 4);
    float*          pQ   = (float*)carve((size_t)nb * 64 * 4);
    float*          bnp1 = (float*)carve(128 * 4);
    float*          bnp2 = (float*)carve(128 * 4);

    const int gcvt = (total8 + 255) / 256;
    const int gw   = (2 * 27 * 4096 + 255) / 256;
    const float invN = 1.0f / (float)n;

    cvt_x_kernel<<<gcvt, 256, 0, stream>>>(x, bufA, total8);
    cvt_w_kernel<<<gw, 256, 0, stream>>>(W1, W2, w1t, w2t);

    conv_mfma<<<nb, 256, 0, stream>>>(bufA, neigh, w1t, bufB, pS, pQ, n);
    bn_stats_kernel<<<64, 256, 0, stream>>>(pS, pQ, g1, b1, bnp1, nb, invN);
    bn_relu_kernel<<<gcvt, 256, 0, stream>>>(bufB, bnp1, bufA, total8);

    conv_mfma<<<nb, 256, 0, stream>>>(bufA, neigh, w2t, bufB, pS, pQ, n);
    bn_stats_kernel<<<64, 256, 0, stream>>>(pS, pQ, g2, b2, bnp2, nb, invN);
    final_kernel<<<gcvt, 256, 0, stream>>>(bufB, x, bnp2, depth, out, total8, n);
}